// Round 15
// baseline (497.639 us; speedup 1.0000x reference)
//
#include <hip/hip_runtime.h>
#include <hip/hip_cooperative_groups.h>

namespace cg = cooperative_groups;

// Self-attention forward. Inputs f32: x[4,2048,1024], Wqkv[1024,3072],
// bqkv[3072], Wout[1024,1024], bout[1024]; mask[4,2048,2048] int32.
// Output f32 [4,2048,1024].
//
// Round-21: single cooperative persistent kernel (1 launch, was 7).
//   Round-14 accounting: dispatch-time sum ~210us vs 299us total ->
//   ~11-12us/launch overhead (confirmed by round 11->13: -2 launches =
//   -15us). Persistent kernel: 256 blocks x 512 thr (96KB LDS = 1
//   block/CU, co-resident), phases prep | K1a+K1b | K2 | softmax | K4 | K5
//   separated by grid.sync(). Every phase = exact multiple of 256 tiles
//   (uniform loops, no ragged barriers). GEMM body = verified round-8
//   core as a __device__ function, unchanged. Dataflow/aliasing identical
//   to round 14. Fallback: if hipLaunchCooperativeKernel errors, run the
//   exact round-14 7-launch path (kept verbatim below).

typedef __attribute__((ext_vector_type(8))) short short8;
typedef __attribute__((ext_vector_type(4))) short short4v;
typedef __attribute__((ext_vector_type(4))) float f32x4;
typedef __attribute__((ext_vector_type(4))) unsigned short us4;
typedef unsigned short u16;

#define SEQ 2048
#define NB 4

static __device__ __forceinline__ u16 f2bf(float f) {
    unsigned int u = __builtin_bit_cast(unsigned int, f);
    u += 0x7fffu + ((u >> 16) & 1u);   // RNE
    return (u16)(u >> 16);
}
static __device__ __forceinline__ float bf2f(u16 h) {
    unsigned int u = ((unsigned int)h) << 16;
    return __builtin_bit_cast(float, u);
}

// async global->LDS, 16 bytes/lane. LDS dest = wave-uniform base + lane*16.
static __device__ __forceinline__ void gld16(u16* l, const u16* g) {
    __builtin_amdgcn_global_load_lds(
        (__attribute__((address_space(1))) void*)(g),
        (__attribute__((address_space(3))) void*)(l),
        16, 0, 0);
}

// bijective XCD swizzle of a flat tile id; requires nwg%8==0.
static __device__ __forceinline__ int xcd_swz(int flat, int nwg) {
    return (flat & 7) * (nwg >> 3) + (flat >> 3);
}

// ---------------------------------------------------------------------------
// bf16 MFMA GEMM tile, 256x128, 4-phase 2-buffer read-ahead pipeline
// (round-8 schedule, harness-verified). Device function form: caller
// supplies LDS (>=96KB), flat tile id, gx (N tiles), batch b.
// C[m][n] = sum_k A[m][k] * Bt[n][k]   (Bt = B^T, [N][K] row-major).
// EPI 0: bf16 out + optional f32 bias.  EPI 1: bf16 out, *scale.
// EPI 2: f32 out + f32 bias.
// EPI 3: bf16 out + bias, TRANSPOSED into vt[4][1024 d][2048 s].
// Requires: flat < gx*(M/256), K%128==0.
// ---------------------------------------------------------------------------
template<int EPI>
static __device__ __forceinline__ void gemm_tile(
    u16* lds, int flat, int gx, int b,
    const u16* __restrict__ Ap, long lda, long aBatch,
    const u16* __restrict__ Bp, long ldb, long bBatch,
    void* __restrict__ Cp, long ldc, long cBatch,
    const float* __restrict__ bias, float scale, int K)
{
    const int tid  = threadIdx.x;
    const int lane = tid & 63;
    const int wave = tid >> 6;          // 0..7
    const int wrq  = wave >> 1;         // 0..3: 32-row band within quadrant
    const int wcq  = wave & 1;          // 0..1: 64-col band within 128 cols
    const int m16  = lane & 15;
    const int quad = lane >> 4;

    const long m0  = (long)(flat / gx) * 256;
    const long n0  = (long)(flat % gx) * 128;

    const u16* A = Ap + (long)b * aBatch;
    const u16* B = Bp + (long)b * bBatch;

    const int srow   = lane >> 3;
    const int schunk = (lane & 7) ^ srow;
    const u16* aP = A + (m0 + wave * 8 + srow) * lda + schunk * 8;
    const u16* bP = B + (n0 + wave * 8 + srow) * ldb + schunk * 8;

    const int cswz = (quad ^ (m16 & 7)) * 8;
    const int arow = wrq * 32 + m16;
    const int brow = wcq * 64 + m16;

    short8 aA[2][2], aB[2][2], b0[2][4], b1[2][4];
    f32x4 acc[2][2][4];                 // [qr][mi][ni]
    #pragma unroll
    for (int qr = 0; qr < 2; qr++)
        #pragma unroll
        for (int mi = 0; mi < 2; mi++)
            #pragma unroll
            for (int ni = 0; ni < 4; ni++)
                acc[qr][mi][ni] = (f32x4){0.f, 0.f, 0.f, 0.f};

    auto STAGE_A = [&](int buf, int h, int toff) {
        u16* l = lds + buf * 24576 + h * 8192 + wave * 512;
        const u16* g = aP + (long)(h * 128) * lda + toff;
        gld16(l, g);
        gld16(l + 4096, g + (long)64 * lda);
    };
    auto STAGE_B = [&](int buf, int toff) {
        u16* l = lds + buf * 24576 + 16384 + wave * 512;
        const u16* g = bP + toff;
        gld16(l, g);
        gld16(l + 4096, g + (long)64 * ldb);
    };
    auto RDA = [&](short8 (&d)[2][2], int buf, int qr) {
        const u16* p = lds + buf * 24576 + qr * 8192 + arow * 64;
        d[0][0] = *(const short8*)(p + cswz);
        d[0][1] = *(const short8*)(p + 1024 + cswz);
        d[1][0] = *(const short8*)(p + (cswz ^ 32));
        d[1][1] = *(const short8*)(p + 1024 + (cswz ^ 32));
    };
    auto RDB = [&](short8 (&d)[2][4], int buf) {
        const u16* p = lds + buf * 24576 + 16384 + brow * 64;
        #pragma unroll
        for (int ks = 0; ks < 2; ks++)
            #pragma unroll
            for (int ni = 0; ni < 4; ni++)
                d[ks][ni] = *(const short8*)(p + ni * 1024 + (cswz ^ (ks * 32)));
    };
    auto MMA = [&](f32x4 (&c)[2][4], const short8 (&a)[2][2],
                   const short8 (&bb)[2][4]) {
        __builtin_amdgcn_s_setprio(1);
        #pragma unroll
        for (int ks = 0; ks < 2; ks++)
            #pragma unroll
            for (int mi = 0; mi < 2; mi++)
                #pragma unroll
                for (int ni = 0; ni < 4; ni++)
                    c[mi][ni] = __builtin_amdgcn_mfma_f32_16x16x32_bf16(
                        a[ks][mi], bb[ks][ni], c[mi][ni], 0, 0, 0);
        __builtin_amdgcn_s_setprio(0);
    };

    const int nt = K >> 6;
    const int niter = nt >> 1;

    // prologue: FIFO = buf0.A0,B0 (4), buf0.A1 (2), buf1.A0,B0 (4).
    STAGE_A(0, 0, 0); STAGE_B(0, 0); STAGE_A(0, 1, 0);
    STAGE_A(1, 0, 64); STAGE_B(1, 64);
    asm volatile("s_waitcnt vmcnt(4)");
    __builtin_amdgcn_s_barrier();
    RDA(aA, 0, 0); RDB(b0, 0);

    #pragma unroll 1
    for (int j = 0; j < niter - 1; ++j) {
        RDA(aB, 0, 1); STAGE_A(1, 1, 64);
        MMA(acc[0], aA, b0);
        asm volatile("s_waitcnt vmcnt(2)");
        __builtin_amdgcn_s_barrier();
        RDA(aA, 1, 0); RDB(b1, 1); STAGE_A(0, 0, 128); STAGE_B(0, 128);
        MMA(acc[1], aB, b0);
        asm volatile("s_waitcnt vmcnt(4)");
        __builtin_amdgcn_s_barrier();
        RDA(aB, 1, 1); STAGE_A(0, 1, 128);
        MMA(acc[0], aA, b1);
        asm volatile("s_waitcnt vmcnt(2)");
        __builtin_amdgcn_s_barrier();
        RDA(aA, 0, 0); RDB(b0, 0); STAGE_A(1, 0, 192); STAGE_B(1, 192);
        MMA(acc[1], aB, b1);
        asm volatile("s_waitcnt vmcnt(4)");
        __builtin_amdgcn_s_barrier();

        aP += 128; bP += 128;
    }

    // peeled final iteration (buf0=nt-2, buf1=nt-1).
    {
        RDA(aB, 0, 1); STAGE_A(1, 1, 64);
        MMA(acc[0], aA, b0);
        asm volatile("s_waitcnt vmcnt(2)");
        __builtin_amdgcn_s_barrier();
        RDA(aA, 1, 0); RDB(b1, 1); STAGE_A(0, 0, 64); STAGE_B(0, 64);
        MMA(acc[1], aB, b0);
        asm volatile("s_waitcnt vmcnt(4)");
        __builtin_amdgcn_s_barrier();
        RDA(aB, 1, 1); STAGE_A(0, 1, 64);
        MMA(acc[0], aA, b1);
        asm volatile("s_waitcnt vmcnt(2)");
        __builtin_amdgcn_s_barrier();
        MMA(acc[1], aB, b1);
    }

    // drain async LDS writes before epilogue (LDS reuse hazard)
    asm volatile("s_waitcnt vmcnt(0)");

    // D mapping per 16x16 frag: col = lane&15, row = quad*4 + r.
    #pragma unroll
    for (int qr = 0; qr < 2; qr++) {
        const long row0 = m0 + qr * 128 + wrq * 32 + quad * 4;
        #pragma unroll
        for (int ni = 0; ni < 4; ni++) {
            const long col = n0 + wcq * 64 + ni * 16 + m16;
            if (EPI == 0) {
                u16* C = (u16*)Cp + (long)b * cBatch;
                const float bv = bias ? bias[col] : 0.f;
                #pragma unroll
                for (int mi = 0; mi < 2; mi++)
                    #pragma unroll
                    for (int r = 0; r < 4; r++)
                        C[(row0 + mi * 16 + r) * ldc + col] =
                            f2bf(acc[qr][mi][ni][r] + bv);
            } else if (EPI == 1) {
                u16* C = (u16*)Cp + (long)b * cBatch;
                #pragma unroll
                for (int mi = 0; mi < 2; mi++)
                    #pragma unroll
                    for (int r = 0; r < 4; r++)
                        C[(row0 + mi * 16 + r) * ldc + col] =
                            f2bf(acc[qr][mi][ni][r] * scale);
            } else if (EPI == 2) {
                float* C = (float*)Cp + (long)b * cBatch;
                const float bv = bias ? bias[col] : 0.f;
                #pragma unroll
                for (int mi = 0; mi < 2; mi++)
                    #pragma unroll
                    for (int r = 0; r < 4; r++)
                        C[(row0 + mi * 16 + r) * ldc + col] =
                            acc[qr][mi][ni][r] + bv;
            } else {
                // EPI 3: transposed V write. Cp = vt[4][1024][2048];
                // ldc = 2048, cBatch = 1024*2048 (round-11 verified).
                u16* C = (u16*)Cp + (m0 >> 11) * cBatch;
                const float bv = bias ? bias[col] : 0.f;
                #pragma unroll
                for (int mi = 0; mi < 2; mi++) {
                    const long sr = (row0 & 2047) + mi * 16;
                    us4 o;
                    #pragma unroll
                    for (int r = 0; r < 4; r++)
                        o[r] = f2bf(acc[qr][mi][ni][r] + bv);
                    *(us4*)(C + col * ldc + sr) = o;
                }
            }
        }
    }
}

// __global__ wrapper (fallback path; round-14 verified launch geometry).
template<int EPI>
__global__ __launch_bounds__(512, 2) void gemm256n128(
    const u16* __restrict__ Ap, long lda, long aBatch,
    const u16* __restrict__ Bp, long ldb, long bBatch,
    void* __restrict__ Cp, long ldc, long cBatch,
    const float* __restrict__ bias, float scale, int K)
{
    __shared__ __attribute__((aligned(16))) u16 lds[49152];
    const int gx = gridDim.x;
    const int flat = xcd_swz(blockIdx.y * gx + blockIdx.x, gx * gridDim.y);
    gemm_tile<EPI>(lds, flat, gx, blockIdx.z, Ap, lda, aBatch, Bp, ldb, bBatch,
                   Cp, ldc, cBatch, bias, scale, K);
}

// Fused preprocessing (fallback; round-13/14 verified).
__global__ __launch_bounds__(256) void prep(
    const float* __restrict__ x, u16* __restrict__ xh,
    const float* __restrict__ Wqkv, u16* __restrict__ wqt,
    const float* __restrict__ Wout, u16* __restrict__ wot)
{
    __shared__ float t[32][33];
    const int id  = blockIdx.x;
    const int tid = threadIdx.x;

    if (id < 4096) {
        const long i = ((long)id * 256 + tid) * 8;
        f32x4 a = *(const f32x4*)(x + i);
        f32x4 b = *(const f32x4*)(x + i + 4);
        short8 o;
        o[0] = (short)f2bf(a.x); o[1] = (short)f2bf(a.y);
        o[2] = (short)f2bf(a.z); o[3] = (short)f2bf(a.w);
        o[4] = (short)f2bf(b.x); o[5] = (short)f2bf(b.y);
        o[6] = (short)f2bf(b.z); o[7] = (short)f2bf(b.w);
        *(short8*)(xh + i) = o;
        return;
    }

    const float* in; u16* out; int C, bx, by;
    if (id < 7168) { const int k = id - 4096; in = Wqkv; out = wqt; C = 3072; bx = k % 96; by = k / 96; }
    else           { const int k = id - 7168; in = Wout; out = wot; C = 1024; bx = k % 32; by = k / 32; }
    const int c0 = bx * 32;
    const int r0 = by * 32;
    const int xx = tid & 31;
    const int yy = (tid >> 5) * 4;
    #pragma unroll
    for (int i = 0; i < 4; i++)
        t[yy + i][xx] = in[(long)(r0 + yy + i) * C + c0 + xx];
    __syncthreads();
    #pragma unroll
    for (int i = 0; i < 4; i++)
        out[(long)(c0 + yy + i) * 1024 + r0 + xx] = f2bf(t[xx][yy + i]);
}

// in-place masked row softmax (fallback; round-14 verified).
__global__ __launch_bounds__(256) void softmax2048(u16* __restrict__ S,
                                                   const int* __restrict__ mask) {
    const long row = blockIdx.x;
    u16* p = S + row * SEQ;
    const int* mrow = mask + row * SEQ;
    const int tid = threadIdx.x;

    short8 v = *(const short8*)(p + tid * 8);
    uint4 mw0 = *(const uint4*)(mrow + tid * 8);
    uint4 mw1 = *(const uint4*)(mrow + tid * 8 + 4);
    const unsigned int* mwv = (const unsigned int*)&mw0;

    float f[8];
    #pragma unroll
    for (int j = 0; j < 8; j++) {
        const unsigned int mv = (j < 4) ? mwv[j] : ((const unsigned int*)&mw1)[j - 4];
        f[j] = (mv == 0u) ? 1e-10f : bf2f((u16)v[j]);
    }

    float m = f[0];
    #pragma unroll
    for (int j = 1; j < 8; j++) m = fmaxf(m, f[j]);
    #pragma unroll
    for (int i = 1; i < 64; i <<= 1) m = fmaxf(m, __shfl_xor(m, i));

    __shared__ float redm[4], reds[4];
    if ((tid & 63) == 0) redm[tid >> 6] = m;
    __syncthreads();
    m = fmaxf(fmaxf(redm[0], redm[1]), fmaxf(redm[2], redm[3]));

    float e[8], s = 0.f;
    #pragma unroll
    for (int j = 0; j < 8; j++) { e[j] = __expf(f[j] - m); s += e[j]; }
    #pragma unroll
    for (int i = 1; i < 64; i <<= 1) s += __shfl_xor(s, i);
    if ((tid & 63) == 0) reds[tid >> 6] = s;
    __syncthreads();
    s = reds[0] + reds[1] + reds[2] + reds[3];

    const float inv = 1.f / s;
    short8 o;
    #pragma unroll
    for (int j = 0; j < 8; j++) o[j] = (short)f2bf(e[j] * inv);
    *(short8*)(p + tid * 8) = o;
}

// ---------------------------------------------------------------------------
// Cooperative persistent kernel: whole pipeline, 256 blocks x 512 threads.
// Phase tile counts are exact multiples of 256 (uniform loops/barriers).
// ---------------------------------------------------------------------------
__global__ __launch_bounds__(512, 2) void fused_attn(
    const float* __restrict__ x, const int* __restrict__ mask,
    const float* __restrict__ Wqkv, const float* __restrict__ bqkv,
    const float* __restrict__ Wout, const float* __restrict__ bout,
    float* __restrict__ out,
    u16* __restrict__ xh, u16* __restrict__ wqt, u16* __restrict__ wot,
    u16* __restrict__ qk, u16* __restrict__ sc,
    u16* __restrict__ attn, u16* __restrict__ vt)
{
    __shared__ __attribute__((aligned(16))) u16 lds[49152];
    cg::grid_group grid = cg::this_grid();
    const int bid = blockIdx.x;     // 0..255
    const int tid = threadIdx.x;    // 0..511

    // ---- PH0: prep (x->xh 8 iters; Wqkv^T 6 iters x2 tiles; Wout^T 2) ----
    #pragma unroll 1
    for (int it = 0; it < 8; ++it) {
        const long i = ((long)(it * 256 + bid)) * 4096 + (long)tid * 8;
        f32x4 a = *(const f32x4*)(x + i);
        f32x4 c = *(const f32x4*)(x + i + 4);
        short8 o;
        o[0] = (short)f2bf(a.x); o[1] = (short)f2bf(a.y);
        o[2] = (short)f2bf(a.z); o[3] = (short)f2bf(a.w);
        o[4] = (short)f2bf(c.x); o[5] = (short)f2bf(c.y);
        o[6] = (short)f2bf(c.z); o[7] = (short)f2bf(c.w);
        *(short8*)(xh + i) = o;
    }
    {
        float (*tt)[32][33] = (float (*)[32][33])lds;   // 8.4 KB overlay
        const int half = tid >> 8;
        const int t256 = tid & 255;
        const int xx = t256 & 31;
        const int yy = (t256 >> 5) * 4;
        #pragma unroll 1
        for (int it = 0; it < 6; ++it) {                // 3072 tiles
            const int tile = (it * 256 + bid) * 2 + half;
            const int c0 = (tile % 96) * 32;
            const int r0 = (tile / 96) * 32;
            __syncthreads();
            #pragma unroll
            for (int i = 0; i < 4; i++)
                tt[half][yy + i][xx] = Wqkv[(long)(r0 + yy + i) * 3072 + c0 + xx];
            __syncthreads();
            #pragma unroll
            for (int i = 0; i < 4; i++)
                wqt[(long)(c0 + yy + i) * 1024 + r0 + xx] = f2bf(tt[half][xx][yy + i]);
        }
        #pragma unroll 1
        for (int it = 0; it < 2; ++it) {                // 1024 tiles
            const int tile = (it * 256 + bid) * 2 + half;
            const int c0 = (tile % 32) * 32;
            const int r0 = (tile / 32) * 32;
            __syncthreads();
            #pragma unroll
            for (int i = 0; i < 4; i++)
                tt[half][yy + i][xx] = Wout[(long)(r0 + yy + i) * 1024 + c0 + xx];
            __syncthreads();
            #pragma unroll
            for (int i = 0; i < 4; i++)
                wot[(long)(c0 + yy + i) * 1024 + r0 + xx] = f2bf(tt[half][xx][yy + i]);
        }
    }
    grid.sync();

    // ---- PH1: K1a qk = x@Wqkv[:, :2048]+b  (512 tiles, gx=16) ----
    #pragma unroll 1
    for (int it = 0; it < 2; ++it) {
        const int flat = xcd_swz(it * 256 + bid, 512);
        gemm_tile<0>(lds, flat, 16, 0, xh, 1024, 0, wqt, 1024, 0,
                     qk, 2048, 0, bqkv, 1.f, 1024);
    }
    // ---- PH2: K1b vt = (x@Wqkv[:, 2048:]+b)^T  (256 tiles, gx=8) ----
    {
        const int flat = xcd_swz(bid, 256);
        gemm_tile<3>(lds, flat, 8, 0, xh, 1024, 0,
                     wqt + (long)2048 * 1024, 1024, 0,
                     vt, SEQ, (long)1024 * SEQ, bqkv + 2048, 1.f, 1024);
    }
    grid.sync();

    // ---- PH3: K2 sc = (Q@K^T)/32  (512 tiles: 4 batches x 128, gx=16) ----
    #pragma unroll 1
    for (int it = 0; it < 2; ++it) {
        const int idx = it * 256 + bid;
        const int bb = idx >> 7;
        const int flat = xcd_swz(idx & 127, 128);
        gemm_tile<1>(lds, flat, 16, bb,
                     qk, 2048, (long)SEQ * 2048,
                     qk + 1024, 2048, (long)SEQ * 2048,
                     sc, SEQ, (long)SEQ * SEQ, nullptr, 0.03125f, 1024);
    }
    grid.sync();

    // ---- PH4: masked row softmax (8192 rows, 32/block, 512 thr/row) ----
    {
        float* redm = (float*)lds;          // 8 floats
        float* reds = (float*)lds + 8;      // 8 floats
        const int lane = tid & 63;
        const int wv   = tid >> 6;          // 0..7
        #pragma unroll 1
        for (int it = 0; it < 32; ++it) {
            const long row = (long)it * 256 + bid;
            u16* p = sc + row * SEQ;
            const int* mrow = mask + row * SEQ;
            short4v v = *(const short4v*)(p + tid * 4);
            uint4 mw = *(const uint4*)(mrow + tid * 4);
            float f[4];
            f[0] = (mw.x == 0u) ? 1e-10f : bf2f((u16)v[0]);
            f[1] = (mw.y == 0u) ? 1e-10f : bf2f((u16)v[1]);
            f[2] = (mw.z == 0u) ? 1e-10f : bf2f((u16)v[2]);
            f[3] = (mw.w == 0u) ? 1e-10f : bf2f((u16)v[3]);

            float m = fmaxf(fmaxf(f[0], f[1]), fmaxf(f[2], f[3]));
            #pragma unroll
            for (int i = 1; i < 64; i <<= 1) m = fmaxf(m, __shfl_xor(m, i));
            if (lane == 0) redm[wv] = m;
            __syncthreads();
            m = redm[0];
            #pragma unroll
            for (int w = 1; w < 8; w++) m = fmaxf(m, redm[w]);

            float e[4], s = 0.f;
            #pragma unroll
            for (int j = 0; j < 4; j++) { e[j] = __expf(f[j] - m); s += e[j]; }
            #pragma unroll
            for (int i = 1; i < 64; i <<= 1) s += __shfl_xor(s, i);
            if (lane == 0) reds[wv] = s;
            __syncthreads();
            s = 0.f;
            #pragma unroll
            for (int w = 0; w < 8; w++) s += reds[w];

            const float inv = 1.f / s;
            short4v o;
            #pragma unroll
            for (int j = 0; j < 4; j++) o[j] = (short)f2bf(e[j] * inv);
            *(short4v*)(p + tid * 4) = o;
            __syncthreads();    // protect redm/reds reuse next iteration
        }
    }
    grid.sync();

    // ---- PH5: K4 attn = P@V  (256 tiles: 4 batches x 64, gx=8) ----
    {
        const int bb = bid >> 6;
        const int flat = xcd_swz(bid & 63, 64);
        gemm_tile<0>(lds, flat, 8, bb,
                     sc, SEQ, (long)SEQ * SEQ,
                     vt, SEQ, (long)1024 * SEQ,
                     attn, 1024, (long)SEQ * 1024, nullptr, 1.f, 2048);
    }
    grid.sync();

    // ---- PH6: K5 out = attn@Wout + bout  (256 tiles, gx=8) ----
    {
        const int flat = xcd_swz(bid, 256);
        gemm_tile<2>(lds, flat, 8, 0, attn, 1024, 0, wot, 1024, 0,
                     out, 1024, 0, bout, 1.f, 1024);
    }
}

extern "C" void kernel_launch(void* const* d_in, const int* in_sizes, int n_in,
                              void* d_out, int out_size, void* d_ws, size_t ws_size,
                              hipStream_t stream) {
    const float* x    = (const float*)d_in[0];
    const int*   mask = (const int*)d_in[1];
    const float* Wqkv = (const float*)d_in[2];
    const float* bqkv = (const float*)d_in[3];
    const float* Wout = (const float*)d_in[4];
    const float* bout = (const float*)d_in[5];
    float* out = (float*)d_out;

    char* ws = (char*)d_ws;
    // ws layout, total 102,760,448 bytes (round-14 layout):
    //   [0,        16777216) xh  bf16 [8192][1024]
    //   [16777216, 23068672) wqt bf16 [3072][1024]
    //   [0,        33554432) sc  bf16 [4][2048][2048]   (aliases xh,wqt after K1)
    //   [33554432, 35651584) wot bf16 [1024][1024]
    //   [35651584, 69206016) qk  bf16 [8192][2048]
    //   [35651584, 52428800) attn bf16 [8192][1024]     (aliases qk after K2)
    //   [85983232,102760448) vt  bf16 [4][1024][2048]
    u16* xh   = (u16*)(ws + 0);
    u16* wqt  = (u16*)(ws + 16777216);
    u16* sc   = (u16*)(ws + 0);
    u16* wot  = (u16*)(ws + 33554432);
    u16* qk   = (u16*)(ws + 35651584);
    u16* attn = (u16*)(ws + 35651584);
    u16* vt   = (u16*)(ws + 85983232);

    // One cooperative persistent launch (256 blocks co-resident at 1/CU).
    void* args[] = {
        (void*)&x, (void*)&mask, (void*)&Wqkv, (void*)&bqkv, (void*)&Wout,
        (void*)&bout, (void*)&out, (void*)&xh, (void*)&wqt, (void*)&wot,
        (void*)&qk, (void*)&sc, (void*)&attn, (void*)&vt };
    hipError_t err = hipLaunchCooperativeKernel(
        reinterpret_cast<void*>(&fused_attn), dim3(256), dim3(512),
        args, 0, stream);
    if (err == hipSuccess) return;

    // Fallback: exact round-14 verified 7-launch path.
    prep<<<dim3(8192), 256, 0, stream>>>(x, xh, Wqkv, wqt, Wout, wot);
    gemm256n128<0><<<dim3(16, 32, 1), 512, 0, stream>>>(
        xh, 1024, 0, wqt, 1024, 0, qk, 2048, 0, bqkv, 1.f, 1024);
    gemm256n128<3><<<dim3(8, 32, 1), 512, 0, stream>>>(
        xh, 1024, 0, wqt + (long)2048 * 1024, 1024, 0,
        vt, SEQ, (long)1024 * SEQ, bqkv + 2048, 1.f, 1024);
    gemm256n128<1><<<dim3(16, 8, NB), 512, 0, stream>>>(
        qk, 2048, (long)SEQ * 2048, qk + 1024, 2048, (long)SEQ * 2048,
        sc, SEQ, (long)SEQ * SEQ, nullptr, 0.03125f, 1024);
    softmax2048<<<dim3(NB * SEQ), 256, 0, stream>>>(sc, mask);
    gemm256n128<0><<<dim3(8, 8, NB), 512, 0, stream>>>(
        sc, SEQ, (long)SEQ * SEQ, vt, SEQ, (long)1024 * SEQ,
        attn, 1024, (long)SEQ * 1024, nullptr, 1.f, 2048);
    gemm256n128<2><<<dim3(8, 32, 1), 512, 0, stream>>>(
        attn, 1024, 0, wot, 1024, 0, out, 1024, 0, bout, 1.f, 1024);
}

// Round 16
// 299.688 us; speedup vs baseline: 1.6605x; 1.6605x over previous
//
#include <hip/hip_runtime.h>

// Self-attention forward. Inputs f32: x[4,2048,1024], Wqkv[1024,3072],
// bqkv[3072], Wout[1024,1024], bout[1024]; mask[4,2048,2048] int32.
// Output f32 [4,2048,1024].
//
// FINAL (round-22): exact revert to the round-14 artifact (299.3us,
// harness-passed) after round-15's cooperative persistent kernel was
// refuted (497us: grid.sync straggler-stacking + serialized per-phase
// GEMM prologues beat the ~11us/launch it saved; MfmaUtil 14.7%).
// Session summary (377 -> 299us, -21%):
//   - GEMM core: 256x128-tile 4-phase 2-buffer read-ahead pipeline
//     (T2 XOR LDS swizzle via pre-swizzled global_load_lds source ->
//     bank conflicts 1.9e7 -> 0; counted vmcnt, never drained in-loop;
//     T1 bijective XCD swizzle; T5 setprio). Five schedule families
//     (2-barrier, 8-phase, read-ahead, ring-3, ring-4@2blk/CU) all
//     plateau at MfmaUtil ~30%; this is the best of them.
//   - Work elimination: transpose_v deleted via EPI3 transposed-V
//     epilogue (K1b writes vt[b][d][s] directly); K2 operands tightened
//     to qk[8192][2048].
//   - Launch fusion: prep = cvt_bf16 + 2x transpose_cvt in one launch.
//     Further fusion (gemm_k1 branchy fuse: replay-divergent; cooperative
//     persistent: -66% perf) failed - 7 launches is the sweet spot.

typedef __attribute__((ext_vector_type(8))) short short8;
typedef __attribute__((ext_vector_type(4))) float f32x4;
typedef __attribute__((ext_vector_type(4))) unsigned short us4;
typedef unsigned short u16;

#define SEQ 2048
#define NB 4

static __device__ __forceinline__ u16 f2bf(float f) {
    unsigned int u = __builtin_bit_cast(unsigned int, f);
    u += 0x7fffu + ((u >> 16) & 1u);   // RNE
    return (u16)(u >> 16);
}
static __device__ __forceinline__ float bf2f(u16 h) {
    unsigned int u = ((unsigned int)h) << 16;
    return __builtin_bit_cast(float, u);
}

// async global->LDS, 16 bytes/lane. LDS dest = wave-uniform base + lane*16.
static __device__ __forceinline__ void gld16(u16* l, const u16* g) {
    __builtin_amdgcn_global_load_lds(
        (__attribute__((address_space(1))) void*)(g),
        (__attribute__((address_space(3))) void*)(l),
        16, 0, 0);
}

// Fused preprocessing, one launch (block-uniform branch):
//   blocks [0,4096):    x f32 -> xh bf16 (8 elems/thread)
//   blocks [4096,7168): Wqkv [1024][3072] -> wqt [3072][1024] (T + cvt)
//   blocks [7168,8192): Wout [1024][1024] -> wot [1024][1024] (T + cvt)
__global__ __launch_bounds__(256) void prep(
    const float* __restrict__ x, u16* __restrict__ xh,
    const float* __restrict__ Wqkv, u16* __restrict__ wqt,
    const float* __restrict__ Wout, u16* __restrict__ wot)
{
    __shared__ float t[32][33];
    const int id  = blockIdx.x;
    const int tid = threadIdx.x;

    if (id < 4096) {
        const long i = ((long)id * 256 + tid) * 8;
        f32x4 a = *(const f32x4*)(x + i);
        f32x4 b = *(const f32x4*)(x + i + 4);
        short8 o;
        o[0] = (short)f2bf(a.x); o[1] = (short)f2bf(a.y);
        o[2] = (short)f2bf(a.z); o[3] = (short)f2bf(a.w);
        o[4] = (short)f2bf(b.x); o[5] = (short)f2bf(b.y);
        o[6] = (short)f2bf(b.z); o[7] = (short)f2bf(b.w);
        *(short8*)(xh + i) = o;
        return;
    }

    const float* in; u16* out; int C, bx, by;
    if (id < 7168) { const int k = id - 4096; in = Wqkv; out = wqt; C = 3072; bx = k % 96; by = k / 96; }
    else           { const int k = id - 7168; in = Wout; out = wot; C = 1024; bx = k % 32; by = k / 32; }
    const int c0 = bx * 32;
    const int r0 = by * 32;
    const int xx = tid & 31;
    const int yy = (tid >> 5) * 4;
    #pragma unroll
    for (int i = 0; i < 4; i++)
        t[yy + i][xx] = in[(long)(r0 + yy + i) * C + c0 + xx];
    __syncthreads();
    #pragma unroll
    for (int i = 0; i < 4; i++)
        out[(long)(c0 + yy + i) * 1024 + r0 + xx] = f2bf(t[xx][yy + i]);
}

// bijective XCD swizzle of the flat (y*gx+x) tile id; requires nwg%8==0.
static __device__ __forceinline__ int xcd_swz(int flat, int nwg) {
    return (flat & 7) * (nwg >> 3) + (flat >> 3);
}

// bf16 MFMA GEMM, 256x128 tile, 4-phase 2-buffer read-ahead pipeline
// (round-8 schedule, harness-verified).
// C[m][n] = sum_k A[m][k] * Bt[n][k]   (Bt = B^T, [N][K] row-major).
// EPI 0: bf16 out + optional f32 bias.  EPI 1: bf16 out, *scale.
// EPI 2: f32 out + f32 bias.
// EPI 3: bf16 out + bias, TRANSPOSED into vt[4][1024 d][2048 s]:
//        vt[m0>>11][col][row%2048] = acc (ushort4 per fragment).
// Stage plan per iter j (buf0=2j, buf1=2j+1): S1=p1:buf1.A1(+64)
//   S2=p2:buf0.{A0,B0}(+128) S3=p3:buf0.A1(+128) S4=p4:buf1.{A0,B0}(+192)
// Reads (for NEXT phase): p1:aB<-buf0.A1[S3(j-1)] p2:aA<-buf1.A0,b1<-
//   buf1.B0[S4(j-1)] p3:aB<-buf1.A1[S1(j)] p4:aA<-buf0.A0,b0<-buf0.B0[S2(j)]
// vmcnt per phase end: p1:2 (retires S4(j-1)) p2:4 (S1) p3:2 (S2) p4:4 (S3).
// Requires: M%256==0, N%128==0, K%128==0, (gx*gy)%8==0.
template<int EPI>
__global__ __launch_bounds__(512, 2) void gemm256n128(
    const u16* __restrict__ Ap, long lda, long aBatch,
    const u16* __restrict__ Bp, long ldb, long bBatch,
    void* __restrict__ Cp, long ldc, long cBatch,
    const float* __restrict__ bias,
    float scale, int K)
{
    // 2 bufs x (A[256][64] + B[128][64]) bf16 = 2 x 48 KB = 96 KB.
    __shared__ __attribute__((aligned(16))) u16 lds[49152];

    const int tid  = threadIdx.x;
    const int lane = tid & 63;
    const int wave = tid >> 6;          // 0..7
    const int wrq  = wave >> 1;         // 0..3: 32-row band within quadrant
    const int wcq  = wave & 1;          // 0..1: 64-col band within 128 cols
    const int m16  = lane & 15;
    const int quad = lane >> 4;
    const int b    = blockIdx.z;

    const int gx = gridDim.x;
    const int flat = xcd_swz(blockIdx.y * gx + blockIdx.x, gx * gridDim.y);
    const long m0  = (long)(flat / gx) * 256;
    const long n0  = (long)(flat % gx) * 128;

    const u16* A = Ap + (long)b * aBatch;
    const u16* B = Bp + (long)b * bBatch;

    const int srow   = lane >> 3;
    const int schunk = (lane & 7) ^ srow;
    const u16* aP = A + (m0 + wave * 8 + srow) * lda + schunk * 8;
    const u16* bP = B + (n0 + wave * 8 + srow) * ldb + schunk * 8;

    const int cswz = (quad ^ (m16 & 7)) * 8;
    const int arow = wrq * 32 + m16;
    const int brow = wcq * 64 + m16;

    short8 aA[2][2], aB[2][2], b0[2][4], b1[2][4];
    f32x4 acc[2][2][4];                 // [qr][mi][ni]
    #pragma unroll
    for (int qr = 0; qr < 2; qr++)
        #pragma unroll
        for (int mi = 0; mi < 2; mi++)
            #pragma unroll
            for (int ni = 0; ni < 4; ni++)
                acc[qr][mi][ni] = (f32x4){0.f, 0.f, 0.f, 0.f};

    auto STAGE_A = [&](int buf, int h, int toff) {
        u16* l = (u16*)lds + buf * 24576 + h * 8192 + wave * 512;
        const u16* g = aP + (long)(h * 128) * lda + toff;
        gld16(l, g);
        gld16(l + 4096, g + (long)64 * lda);
    };
    auto STAGE_B = [&](int buf, int toff) {
        u16* l = (u16*)lds + buf * 24576 + 16384 + wave * 512;
        const u16* g = bP + toff;
        gld16(l, g);
        gld16(l + 4096, g + (long)64 * ldb);
    };
    auto RDA = [&](short8 (&d)[2][2], int buf, int qr) {
        const u16* p = (const u16*)lds + buf * 24576 + qr * 8192 + arow * 64;
        d[0][0] = *(const short8*)(p + cswz);
        d[0][1] = *(const short8*)(p + 1024 + cswz);
        d[1][0] = *(const short8*)(p + (cswz ^ 32));
        d[1][1] = *(const short8*)(p + 1024 + (cswz ^ 32));
    };
    auto RDB = [&](short8 (&d)[2][4], int buf) {
        const u16* p = (const u16*)lds + buf * 24576 + 16384 + brow * 64;
        #pragma unroll
        for (int ks = 0; ks < 2; ks++)
            #pragma unroll
            for (int ni = 0; ni < 4; ni++)
                d[ks][ni] = *(const short8*)(p + ni * 1024 + (cswz ^ (ks * 32)));
    };
    auto MMA = [&](f32x4 (&c)[2][4], const short8 (&a)[2][2],
                   const short8 (&bb)[2][4]) {
        __builtin_amdgcn_s_setprio(1);
        #pragma unroll
        for (int ks = 0; ks < 2; ks++)
            #pragma unroll
            for (int mi = 0; mi < 2; mi++)
                #pragma unroll
                for (int ni = 0; ni < 4; ni++)
                    c[mi][ni] = __builtin_amdgcn_mfma_f32_16x16x32_bf16(
                        a[ks][mi], bb[ks][ni], c[mi][ni], 0, 0, 0);
        __builtin_amdgcn_s_setprio(0);
    };

    const int nt = K >> 6;
    const int niter = nt >> 1;

    // prologue: FIFO = buf0.A0,B0 (4), buf0.A1 (2), buf1.A0,B0 (4).
    // vmcnt(4) retires buf0 entirely (pre-reads + p1's read).
    STAGE_A(0, 0, 0); STAGE_B(0, 0); STAGE_A(0, 1, 0);
    STAGE_A(1, 0, 64); STAGE_B(1, 64);
    asm volatile("s_waitcnt vmcnt(4)");
    __builtin_amdgcn_s_barrier();
    RDA(aA, 0, 0); RDB(b0, 0);

    #pragma unroll 1
    for (int j = 0; j < niter - 1; ++j) {
        // p1: buf0.q0 [aA,b0] ; read aB<-buf0.A1
        RDA(aB, 0, 1); STAGE_A(1, 1, 64);
        MMA(acc[0], aA, b0);
        asm volatile("s_waitcnt vmcnt(2)");
        __builtin_amdgcn_s_barrier();
        // p2: buf0.q1 [aB,b0] ; read aA<-buf1.A0, b1<-buf1.B
        RDA(aA, 1, 0); RDB(b1, 1); STAGE_A(0, 0, 128); STAGE_B(0, 128);
        MMA(acc[1], aB, b0);
        asm volatile("s_waitcnt vmcnt(4)");
        __builtin_amdgcn_s_barrier();
        // p3: buf1.q0 [aA,b1] ; read aB<-buf1.A1
        RDA(aB, 1, 1); STAGE_A(0, 1, 128);
        MMA(acc[0], aA, b1);
        asm volatile("s_waitcnt vmcnt(2)");
        __builtin_amdgcn_s_barrier();
        // p4: buf1.q1 [aB,b1] ; read aA<-buf0.A0, b0<-buf0.B (tile 2j+2)
        RDA(aA, 0, 0); RDB(b0, 0); STAGE_A(1, 0, 192); STAGE_B(1, 192);
        MMA(acc[1], aB, b1);
        asm volatile("s_waitcnt vmcnt(4)");
        __builtin_amdgcn_s_barrier();

        aP += 128; bP += 128;
    }

    // peeled final iteration (buf0=nt-2, buf1=nt-1): p1 stage real;
    // p2..p4 dead (clamped +64); p4's next-tile reads skipped.
    {
        RDA(aB, 0, 1); STAGE_A(1, 1, 64);
        MMA(acc[0], aA, b0);
        asm volatile("s_waitcnt vmcnt(2)");
        __builtin_amdgcn_s_barrier();
        RDA(aA, 1, 0); RDB(b1, 1); STAGE_A(0, 0, 64); STAGE_B(0, 64);
        MMA(acc[1], aB, b0);
        asm volatile("s_waitcnt vmcnt(4)");
        __builtin_amdgcn_s_barrier();
        RDA(aB, 1, 1); STAGE_A(0, 1, 64);
        MMA(acc[0], aA, b1);
        asm volatile("s_waitcnt vmcnt(2)");
        __builtin_amdgcn_s_barrier();
        MMA(acc[1], aB, b1);
    }

    // drain async LDS writes before epilogue/endpgm (LDS realloc hazard)
    asm volatile("s_waitcnt vmcnt(0)");

    // D mapping per 16x16 frag: col = lane&15, row = quad*4 + r.
    #pragma unroll
    for (int qr = 0; qr < 2; qr++) {
        const long row0 = m0 + qr * 128 + wrq * 32 + quad * 4;
        #pragma unroll
        for (int ni = 0; ni < 4; ni++) {
            const long col = n0 + wcq * 64 + ni * 16 + m16;
            if (EPI == 0) {
                u16* C = (u16*)Cp + (long)b * cBatch;
                const float bv = bias ? bias[col] : 0.f;
                #pragma unroll
                for (int mi = 0; mi < 2; mi++)
                    #pragma unroll
                    for (int r = 0; r < 4; r++)
                        C[(row0 + mi * 16 + r) * ldc + col] =
                            f2bf(acc[qr][mi][ni][r] + bv);
            } else if (EPI == 1) {
                u16* C = (u16*)Cp + (long)b * cBatch;
                #pragma unroll
                for (int mi = 0; mi < 2; mi++)
                    #pragma unroll
                    for (int r = 0; r < 4; r++)
                        C[(row0 + mi * 16 + r) * ldc + col] =
                            f2bf(acc[qr][mi][ni][r] * scale);
            } else if (EPI == 2) {
                float* C = (float*)Cp + (long)b * cBatch;
                const float bv = bias ? bias[col] : 0.f;
                #pragma unroll
                for (int mi = 0; mi < 2; mi++)
                    #pragma unroll
                    for (int r = 0; r < 4; r++)
                        C[(row0 + mi * 16 + r) * ldc + col] =
                            acc[qr][mi][ni][r] + bv;
            } else {
                // EPI 3: transposed V write. Cp = vt[4][1024][2048];
                // ldc = 2048 (s-stride), cBatch = 1024*2048. Blocks are
                // 256 rows, 2048%256==0 -> batch uniform per block.
                u16* C = (u16*)Cp + (m0 >> 11) * cBatch;
                const float bv = bias ? bias[col] : 0.f;
                #pragma unroll
                for (int mi = 0; mi < 2; mi++) {
                    const long sr = (row0 & 2047) + mi * 16;
                    us4 o;
                    #pragma unroll
                    for (int r = 0; r < 4; r++)
                        o[r] = f2bf(acc[qr][mi][ni][r] + bv);
                    *(us4*)(C + col * ldc + sr) = o;
                }
            }
        }
    }
}

// in-place masked row softmax over 2048 bf16 (f32 math). 1 block per row.
__global__ __launch_bounds__(256) void softmax2048(u16* __restrict__ S,
                                                   const int* __restrict__ mask) {
    const long row = blockIdx.x;
    u16* p = S + row * SEQ;
    const int* mrow = mask + row * SEQ;
    const int tid = threadIdx.x;

    short8 v = *(const short8*)(p + tid * 8);
    uint4 mw0 = *(const uint4*)(mrow + tid * 8);
    uint4 mw1 = *(const uint4*)(mrow + tid * 8 + 4);
    const unsigned int* mwv = (const unsigned int*)&mw0;

    float f[8];
    #pragma unroll
    for (int j = 0; j < 8; j++) {
        const unsigned int mv = (j < 4) ? mwv[j] : ((const unsigned int*)&mw1)[j - 4];
        f[j] = (mv == 0u) ? 1e-10f : bf2f((u16)v[j]);
    }

    float m = f[0];
    #pragma unroll
    for (int j = 1; j < 8; j++) m = fmaxf(m, f[j]);
    #pragma unroll
    for (int i = 1; i < 64; i <<= 1) m = fmaxf(m, __shfl_xor(m, i));

    __shared__ float redm[4], reds[4];
    if ((tid & 63) == 0) redm[tid >> 6] = m;
    __syncthreads();
    m = fmaxf(fmaxf(redm[0], redm[1]), fmaxf(redm[2], redm[3]));

    float e[8], s = 0.f;
    #pragma unroll
    for (int j = 0; j < 8; j++) { e[j] = __expf(f[j] - m); s += e[j]; }
    #pragma unroll
    for (int i = 1; i < 64; i <<= 1) s += __shfl_xor(s, i);
    if ((tid & 63) == 0) reds[tid >> 6] = s;
    __syncthreads();
    s = reds[0] + reds[1] + reds[2] + reds[3];

    const float inv = 1.f / s;
    short8 o;
    #pragma unroll
    for (int j = 0; j < 8; j++) o[j] = (short)f2bf(e[j] * inv);
    *(short8*)(p + tid * 8) = o;
}

extern "C" void kernel_launch(void* const* d_in, const int* in_sizes, int n_in,
                              void* d_out, int out_size, void* d_ws, size_t ws_size,
                              hipStream_t stream) {
    const float* x    = (const float*)d_in[0];
    const int*   mask = (const int*)d_in[1];
    const float* Wqkv = (const float*)d_in[2];
    const float* bqkv = (const float*)d_in[3];
    const float* Wout = (const float*)d_in[4];
    const float* bout = (const float*)d_in[5];
    float* out = (float*)d_out;

    char* ws = (char*)d_ws;
    // ws layout, total 102,760,448 bytes:
    //   [0,        16777216) xh  bf16 [8192][1024]          (prep -> K1a/K1b)
    //   [16777216, 23068672) wqt bf16 [3072][1024]          (prep -> K1a/K1b)
    //   [0,        33554432) sc  bf16 [4][2048][2048]       (K2 -> K4; xh,wqt dead)
    //   [33554432, 35651584) wot bf16 [1024][1024]          (prep -> K5)
    //   [35651584, 69206016) qk  bf16 [8192][2048]          (K1a -> K2)
    //   [35651584, 52428800) attn bf16 [8192][1024]         (K4 -> K5; qk dead)
    //   [85983232,102760448) vt  bf16 [4][1024][2048]       (K1b -> K4)
    u16* xh   = (u16*)(ws + 0);
    u16* wqt  = (u16*)(ws + 16777216);
    u16* sc   = (u16*)(ws + 0);
    u16* wot  = (u16*)(ws + 33554432);
    u16* qk   = (u16*)(ws + 35651584);
    u16* attn = (u16*)(ws + 35651584);
    u16* vt   = (u16*)(ws + 85983232);

    // P: all input conversions/transposes, one launch (8192 blocks)
    prep<<<dim3(8192), 256, 0, stream>>>(x, xh, Wqkv, wqt, Wout, wot);

    // K1a: qk = x @ Wqkv[:, :2048] + bqkv[:2048]  (M=8192, N=2048, K=1024)
    //      16x32 = 512 blocks = 2.0 exact rounds
    gemm256n128<0><<<dim3(16, 32, 1), 512, 0, stream>>>(
        xh, 1024, 0, wqt, 1024, 0, qk, 2048, 0, bqkv, 1.f, 1024);

    // K1b: vt = (x @ Wqkv[:, 2048:] + bqkv[2048:])^T per batch
    //      (M=8192, N=1024, K=1024), transposed epilogue -> vt[b][d][s]
    //      8x32 = 256 blocks = 1.0 round
    gemm256n128<3><<<dim3(8, 32, 1), 512, 0, stream>>>(
        xh, 1024, 0, wqt + (long)2048 * 1024, 1024, 0,
        vt, SEQ, (long)1024 * SEQ, bqkv + 2048, 1.f, 1024);

    // K2: sc[b] = (Q[b] @ K[b]^T)/32   (M=N=2048, K=1024), bf16 out
    //     A = qk cols 0-1023 (Q), B = qk cols 1024-2047 (K), lda=ldb=2048
    //     16x8x4 = 512 blocks = 2.0 exact rounds
    gemm256n128<1><<<dim3(16, 8, NB), 512, 0, stream>>>(
        qk, 2048, (long)SEQ * 2048, qk + 1024, 2048, (long)SEQ * 2048,
        sc, SEQ, (long)SEQ * SEQ, nullptr, 0.03125f, 1024);

    // K3: masked softmax rows (mask==0 -> 1e-10, f32 math, bf16 storage)
    softmax2048<<<dim3(NB * SEQ), 256, 0, stream>>>(sc, mask);

    // K4: attn[b] = P[b] @ V[b]   (M=2048, N=1024, K=2048), bf16 out
    //     8x8x4 = 256 blocks = 1.0 round
    gemm256n128<0><<<dim3(8, 8, NB), 512, 0, stream>>>(
        sc, SEQ, (long)SEQ * SEQ, vt, SEQ, (long)1024 * SEQ,
        attn, 1024, (long)SEQ * 1024, nullptr, 1.f, 2048);

    // K5: out = attn @ Wout + bout   (M=8192, N=1024, K=1024), f32 out
    //     8x32 = 256 blocks = 1.0 round
    gemm256n128<2><<<dim3(8, 32, 1), 512, 0, stream>>>(
        attn, 1024, 0, wot, 1024, 0, out, 1024, 0, bout, 1.f, 1024);
}